// Round 1
// baseline (550.254 us; speedup 1.0000x reference)
//
#include <hip/hip_runtime.h>

// Separable 41-tap Gaussian blur, reflect-pad 20, depthwise over [16,6,512,512] fp32.
// Fused single kernel: horizontal pass -> LDS tmp, vertical pass -> out.

#define TW 64
#define TH 128
#define KS 41
#define PAD 20
#define H 512
#define W 512
#define CH 6
#define TMPH (TH + 2 * PAD)  // 168

__device__ __forceinline__ int reflect_idx(int i, int n) {
    if (i < 0) i = -i;                 // -1 -> 1 (PyTorch/jnp 'reflect', no edge repeat)
    if (i >= n) i = 2 * n - 2 - i;     // n -> n-2
    return i;
}

__global__ __launch_bounds__(256, 3)
void gauss_blur_sep_kernel(const float* __restrict__ x,
                           const float* __restrict__ w,
                           float* __restrict__ out) {
    __shared__ float g_s[KS];
    __shared__ float tmp[TMPH * TW];   // 168*64*4 = 43 KB

    const int tid = threadIdx.x;
    const int bx = blockIdx.x;   // 0..7   x tiles
    const int by = blockIdx.y;   // 0..3   y tiles
    const int bz = blockIdx.z;   // 0..95  = b*CH + c
    const int c  = bz % CH;

    // 1D kernel = row sums of the 2D kernel (exact separable factorization,
    // since w2d[i][j] = g[i]*g[j] with sum(g)=1).
    if (tid < KS) {
        const float* wr = w + (size_t)c * KS * KS + (size_t)tid * KS;
        float s = 0.f;
        #pragma unroll
        for (int j = 0; j < KS; ++j) s += wr[j];
        g_s[tid] = s;
    }
    __syncthreads();

    float gr[KS];
    #pragma unroll
    for (int j = 0; j < KS; ++j) gr[j] = g_s[j];

    const size_t img_off = (size_t)bz * (H * W);
    const float* img = x + img_off;
    const int x_tile = bx * TW;

    // ---- Step 1: horizontal conv -> tmp[TMPH][TW] ----
    // 168 rows * 8 groups-of-8 = 1344 groups over 256 threads.
    for (int gid = tid; gid < TMPH * (TW / 8); gid += 256) {
        const int r  = gid >> 3;                       // tmp row 0..167
        const int gx = gid & 7;                        // x group
        const int gy = reflect_idx(by * TH - PAD + r, H);
        const int x0 = x_tile + gx * 8;                // output x base
        const float* row = img + (size_t)gy * W;

        float buf[48];
        if (x0 >= PAD && x0 + 27 <= W - 1) {
            // aligned: x0-20 is a multiple of 4 (x0 multiple of 8)
            const float4* p = (const float4*)(row + x0 - PAD);
            #pragma unroll
            for (int m = 0; m < 12; ++m) {
                float4 v = p[m];
                buf[4 * m + 0] = v.x;
                buf[4 * m + 1] = v.y;
                buf[4 * m + 2] = v.z;
                buf[4 * m + 3] = v.w;
            }
        } else {
            #pragma unroll
            for (int j = 0; j < 48; ++j)
                buf[j] = row[reflect_idx(x0 - PAD + j, W)];
        }

        float s[8];
        #pragma unroll
        for (int k = 0; k < 8; ++k) s[k] = 0.f;
        #pragma unroll
        for (int j = 0; j < KS; ++j) {
            #pragma unroll
            for (int k = 0; k < 8; ++k) s[k] += gr[j] * buf[j + k];
        }
        float* dst = &tmp[r * TW + gx * 8];
        #pragma unroll
        for (int k = 0; k < 8; ++k) dst[k] = s[k];
    }
    __syncthreads();

    // ---- Step 2: vertical conv tmp -> out ----
    // lane x = tid&63; 4 y-groups of 32 rows each, processed in 2 chunks of 16.
    const int lx = tid & 63;
    const int yg = tid >> 6;   // 0..3
    float* o = out + img_off;

    #pragma unroll
    for (int cc = 0; cc < 2; ++cc) {
        const int yc = yg * 32 + cc * 16;  // output-y base within tile
        float col[56];
        #pragma unroll
        for (int i = 0; i < 56; ++i)
            col[i] = tmp[(yc + i) * TW + lx];   // stride-1 across lanes: conflict-free
        #pragma unroll
        for (int y = 0; y < 16; ++y) {
            float s = 0.f;
            #pragma unroll
            for (int j = 0; j < KS; ++j) s += gr[j] * col[y + j];
            o[(size_t)(by * TH + yc + y) * W + x_tile + lx] = s;
        }
    }
}

extern "C" void kernel_launch(void* const* d_in, const int* in_sizes, int n_in,
                              void* d_out, int out_size, void* d_ws, size_t ws_size,
                              hipStream_t stream) {
    const float* x = (const float*)d_in[0];   // [16,6,512,512]
    const float* w = (const float*)d_in[1];   // [6,1,41,41]
    float* out = (float*)d_out;               // [16,6,512,512]
    (void)in_sizes; (void)n_in; (void)out_size; (void)d_ws; (void)ws_size;

    dim3 grid(W / TW, H / TH, 16 * CH);       // (8, 4, 96)
    gauss_blur_sep_kernel<<<grid, 256, 0, stream>>>(x, w, out);
}

// Round 2
// 263.644 us; speedup vs baseline: 2.0871x; 2.0871x over previous
//
#include <hip/hip_runtime.h>

#define KS 41
#define PAD 20
#define H 512
#define W 512
#define CH 6

__device__ __forceinline__ int reflect_idx(int i, int n) {
    if (i < 0) i = -i;
    if (i >= n) i = 2 * n - 2 - i;
    return i;
}

__device__ __forceinline__ int reflect511(int i) {
    // valid for i in (-512, 1022)
    return (H - 1) - abs((H - 1) - abs(i));
}

// ---------------- Pass 1: horizontal blur, x -> ws ----------------
// One wave per image row. Row + reflect halo staged in per-wave LDS.
__global__ __launch_bounds__(256, 4)
void gauss_h_kernel(const float* __restrict__ x, const float* __restrict__ w,
                    float* __restrict__ ws) {
    __shared__ float g_s[KS];
    __shared__ float rowbuf[4][576];   // [wave][20 halo + 512 + 20 halo + pad]

    const int tid = threadIdx.x;
    const int wv = tid >> 6;
    const int l  = tid & 63;
    const int img = blockIdx.y;              // 0..95 (= b*CH + c)
    const int c   = img % CH;
    const int row = blockIdx.x * 4 + wv;     // 0..511

    // 1D kernel = row sums of the (separable) 2D kernel
    if (tid < KS) {
        const float* wr = w + (size_t)c * KS * KS + (size_t)tid * KS;
        float s = 0.f;
        #pragma unroll
        for (int j = 0; j < KS; ++j) s += wr[j];
        g_s[tid] = s;
    }

    // stage row: lane l holds x = 8l..8l+7
    const float* src = x + ((size_t)img * H + row) * W;
    float4 v0 = ((const float4*)src)[2 * l];
    float4 v1 = ((const float4*)src)[2 * l + 1];
    float* L = rowbuf[wv];
    ((float4*)(L + PAD + 8 * l))[0] = v0;
    ((float4*)(L + PAD + 8 * l))[1] = v1;
    __syncthreads();

    // reflect halo: L[p] (p<20) = row[20-p];  L[532+q] = row[510-q]
    if (l < 2 * PAD) {
        const int dst  = (l < PAD) ? l        : (W + l);       // 0..19 | 532..551
        const int srcp = (l < PAD) ? (40 - l) : (550 - l);
        float hv = L[srcp];
        L[dst] = hv;
    }
    __syncthreads();

    float g[KS];
    #pragma unroll
    for (int j = 0; j < KS; ++j) g[j] = g_s[j];

    float* dst = ws + ((size_t)img * H + row) * W;
    #pragma unroll
    for (int k = 0; k < 2; ++k) {
        const int p = 256 * k + 4 * l;       // output quad base (padded == output coords)
        float win[44];
        #pragma unroll
        for (int m = 0; m < 11; ++m) {       // lane-stride-16B b128: conflict-free
            float4 t4 = ((const float4*)(L + p))[m];
            win[4 * m + 0] = t4.x; win[4 * m + 1] = t4.y;
            win[4 * m + 2] = t4.z; win[4 * m + 3] = t4.w;
        }
        float acc[4] = {0.f, 0.f, 0.f, 0.f};
        #pragma unroll
        for (int j = 0; j < KS; ++j) {
            #pragma unroll
            for (int i = 0; i < 4; ++i) acc[i] += g[j] * win[i + j];
        }
        *((float4*)(dst + p)) = make_float4(acc[0], acc[1], acc[2], acc[3]);
    }
}

// ---------------- Pass 2: vertical blur, ws -> out ----------------
// Thread owns a 2-float column strip x=2t, 16 output rows; 56 independent
// coalesced float2 row loads scatter-accumulate into acc[16].
__global__ __launch_bounds__(256, 4)
void gauss_v_kernel(const float* __restrict__ ws, const float* __restrict__ w,
                    float* __restrict__ out) {
    __shared__ float g_s[KS];
    const int tid = threadIdx.x;
    const int img = blockIdx.y;          // 0..95
    const int c   = img % CH;
    const int y0  = blockIdx.x * 16;     // 0..496

    if (tid < KS) {
        const float* wr = w + (size_t)c * KS * KS + (size_t)tid * KS;
        float s = 0.f;
        #pragma unroll
        for (int j = 0; j < KS; ++j) s += wr[j];
        g_s[tid] = s;
    }
    __syncthreads();

    float g[KS];
    #pragma unroll
    for (int j = 0; j < KS; ++j) g[j] = g_s[j];

    const float* sbase = ws + (size_t)img * H * W + 2 * tid;
    float* obase = out + ((size_t)img * H + y0) * W + 2 * tid;

    float2 acc[16];
    #pragma unroll
    for (int r = 0; r < 16; ++r) acc[r] = make_float2(0.f, 0.f);

    #pragma unroll
    for (int i = 0; i < 56; ++i) {
        const int rr = reflect511(y0 - PAD + i);
        const float2 v = *(const float2*)(sbase + (size_t)rr * W);
        #pragma unroll
        for (int r = 0; r < 16; ++r) {
            const int j = i - r;
            if (j >= 0 && j < KS) {
                acc[r].x += g[j] * v.x;
                acc[r].y += g[j] * v.y;
            }
        }
    }
    #pragma unroll
    for (int r = 0; r < 16; ++r)
        *((float2*)(obase + (size_t)r * W)) = acc[r];
}

// ---------------- Fallback: known-correct fused kernel ----------------
#define TW 64
#define TH 128
#define TMPH (TH + 2 * PAD)  // 168

__global__ __launch_bounds__(256, 3)
void gauss_blur_fused_kernel(const float* __restrict__ x,
                             const float* __restrict__ w,
                             float* __restrict__ out) {
    __shared__ float g_s[KS];
    __shared__ float tmp[TMPH * TW];

    const int tid = threadIdx.x;
    const int bx = blockIdx.x, by = blockIdx.y, bz = blockIdx.z;
    const int c = bz % CH;

    if (tid < KS) {
        const float* wr = w + (size_t)c * KS * KS + (size_t)tid * KS;
        float s = 0.f;
        #pragma unroll
        for (int j = 0; j < KS; ++j) s += wr[j];
        g_s[tid] = s;
    }
    __syncthreads();

    float gr[KS];
    #pragma unroll
    for (int j = 0; j < KS; ++j) gr[j] = g_s[j];

    const size_t img_off = (size_t)bz * (H * W);
    const float* img = x + img_off;
    const int x_tile = bx * TW;

    for (int gid = tid; gid < TMPH * (TW / 8); gid += 256) {
        const int r  = gid >> 3;
        const int gx = gid & 7;
        const int gy = reflect_idx(by * TH - PAD + r, H);
        const int x0 = x_tile + gx * 8;
        const float* row = img + (size_t)gy * W;

        float buf[48];
        if (x0 >= PAD && x0 + 27 <= W - 1) {
            const float4* p = (const float4*)(row + x0 - PAD);
            #pragma unroll
            for (int m = 0; m < 12; ++m) {
                float4 v = p[m];
                buf[4 * m + 0] = v.x; buf[4 * m + 1] = v.y;
                buf[4 * m + 2] = v.z; buf[4 * m + 3] = v.w;
            }
        } else {
            #pragma unroll
            for (int j = 0; j < 48; ++j)
                buf[j] = row[reflect_idx(x0 - PAD + j, W)];
        }

        float s[8];
        #pragma unroll
        for (int k = 0; k < 8; ++k) s[k] = 0.f;
        #pragma unroll
        for (int j = 0; j < KS; ++j) {
            #pragma unroll
            for (int k = 0; k < 8; ++k) s[k] += gr[j] * buf[j + k];
        }
        float* dstp = &tmp[r * TW + gx * 8];
        #pragma unroll
        for (int k = 0; k < 8; ++k) dstp[k] = s[k];
    }
    __syncthreads();

    const int lx = tid & 63;
    const int yg = tid >> 6;
    float* o = out + img_off;

    #pragma unroll
    for (int cc = 0; cc < 2; ++cc) {
        const int yc = yg * 32 + cc * 16;
        float col[56];
        #pragma unroll
        for (int i = 0; i < 56; ++i)
            col[i] = tmp[(yc + i) * TW + lx];
        #pragma unroll
        for (int y = 0; y < 16; ++y) {
            float s = 0.f;
            #pragma unroll
            for (int j = 0; j < KS; ++j) s += gr[j] * col[y + j];
            o[(size_t)(by * TH + yc + y) * W + x_tile + lx] = s;
        }
    }
}

extern "C" void kernel_launch(void* const* d_in, const int* in_sizes, int n_in,
                              void* d_out, int out_size, void* d_ws, size_t ws_size,
                              hipStream_t stream) {
    const float* x = (const float*)d_in[0];   // [16,6,512,512]
    const float* w = (const float*)d_in[1];   // [6,1,41,41]
    float* out = (float*)d_out;
    (void)in_sizes; (void)n_in; (void)out_size;

    const size_t need = (size_t)16 * CH * H * W * sizeof(float);
    if (ws_size >= need) {
        float* ws = (float*)d_ws;
        gauss_h_kernel<<<dim3(H / 4, 16 * CH), 256, 0, stream>>>(x, w, ws);
        gauss_v_kernel<<<dim3(H / 16, 16 * CH), 256, 0, stream>>>(ws, w, out);
    } else {
        dim3 grid(W / TW, H / TH, 16 * CH);
        gauss_blur_fused_kernel<<<grid, 256, 0, stream>>>(x, w, out);
    }
}

// Round 3
// 263.510 us; speedup vs baseline: 2.0882x; 1.0005x over previous
//
#include <hip/hip_runtime.h>

#define KS 41
#define PAD 20
#define H 512
#define W 512
#define CH 6

__device__ __forceinline__ int reflect_idx(int i, int n) {
    if (i < 0) i = -i;
    if (i >= n) i = 2 * n - 2 - i;
    return i;
}

__device__ __forceinline__ int reflect511(int i) {
    // valid for i in (-512, 1022)
    return (H - 1) - abs((H - 1) - abs(i));
}

__device__ __forceinline__ float uniform_f(float v) {
    // wave-uniform value -> SGPR (coefficients cost 0 VGPRs this way)
    return __uint_as_float(__builtin_amdgcn_readfirstlane(__float_as_uint(v)));
}

// ---------------- Pass 1: horizontal blur, x -> ws ----------------
// One wave per image row; row + reflect halo staged in per-wave LDS.
// Coeffs in SGPRs; window in 44 VGPRs via 11 b128 LDS reads (16B lane stride).
__global__ __launch_bounds__(256, 4)
void gauss_h_kernel(const float* __restrict__ x, const float* __restrict__ w,
                    float* __restrict__ ws) {
    __shared__ float g_s[KS];
    __shared__ float rowbuf[4][576];   // [wave][20 halo + 512 + 20 halo + pad]

    const int tid = threadIdx.x;
    const int wv = tid >> 6;
    const int l  = tid & 63;
    const int img = blockIdx.y;              // 0..95 (= b*CH + c)
    const int c   = img % CH;
    const int row = blockIdx.x * 4 + wv;     // 0..511

    // 1D kernel = row sums of the (separable) 2D kernel
    if (tid < KS) {
        const float* wr = w + (size_t)c * KS * KS + (size_t)tid * KS;
        float s = 0.f;
        #pragma unroll
        for (int j = 0; j < KS; ++j) s += wr[j];
        g_s[tid] = s;
    }

    // stage row at 16B lane stride: lane l holds quads l and l+64
    const float4* src4 = (const float4*)(x + ((size_t)img * H + row) * W);
    float4 v0 = src4[l];
    float4 v1 = src4[l + 64];
    float* L = rowbuf[wv];
    *(float4*)(L + PAD + 4 * l)       = v0;   // floats 0..255
    *(float4*)(L + PAD + 256 + 4 * l) = v1;   // floats 256..511
    __syncthreads();

    // reflect halo: L[p] (p<20) = row[20-p];  L[532+q] = row[510-q]
    if (l < 2 * PAD) {
        const int dst  = (l < PAD) ? l        : (W + l);       // 0..19 | 532..551
        const int srcp = (l < PAD) ? (40 - l) : (550 - l);
        float hv = L[srcp];
        L[dst] = hv;
    }
    __syncthreads();

    // coefficients -> SGPRs (broadcast LDS read + readfirstlane)
    float gk[KS];
    #pragma unroll
    for (int j = 0; j < KS; ++j) gk[j] = uniform_f(g_s[j]);

    float* dst = ws + ((size_t)img * H + row) * W;
    #pragma unroll
    for (int k = 0; k < 2; ++k) {
        const int x0 = 256 * k + 4 * l;      // output quad base (padded coord == x0)
        float win[44];
        #pragma unroll
        for (int m = 0; m < 11; ++m) {       // b128, 16B lane stride: minimal aliasing
            float4 q = *(const float4*)(L + x0 + 4 * m);
            win[4 * m + 0] = q.x; win[4 * m + 1] = q.y;
            win[4 * m + 2] = q.z; win[4 * m + 3] = q.w;
        }
        float a0 = 0.f, a1 = 0.f, a2 = 0.f, a3 = 0.f;
        #pragma unroll
        for (int j = 0; j < KS; ++j) {
            const float gj = gk[j];
            a0 += gj * win[j + 0];
            a1 += gj * win[j + 1];
            a2 += gj * win[j + 2];
            a3 += gj * win[j + 3];
        }
        *(float4*)(dst + x0) = make_float4(a0, a1, a2, a3);
    }
}

// ---------------- Pass 2: vertical blur, ws -> out ----------------
// Thread owns a 2-float column strip, 16 output rows; 56 independent
// coalesced float2 row loads scatter-accumulate into acc[16].
__global__ __launch_bounds__(256, 4)
void gauss_v_kernel(const float* __restrict__ ws, const float* __restrict__ w,
                    float* __restrict__ out) {
    __shared__ float g_s[KS];
    const int tid = threadIdx.x;
    const int img = blockIdx.y;          // 0..95
    const int c   = img % CH;
    const int y0  = blockIdx.x * 16;     // 0..496

    if (tid < KS) {
        const float* wr = w + (size_t)c * KS * KS + (size_t)tid * KS;
        float s = 0.f;
        #pragma unroll
        for (int j = 0; j < KS; ++j) s += wr[j];
        g_s[tid] = s;
    }
    __syncthreads();

    float gk[KS];
    #pragma unroll
    for (int j = 0; j < KS; ++j) gk[j] = uniform_f(g_s[j]);

    const float* sbase = ws + (size_t)img * H * W + 2 * tid;
    float* obase = out + ((size_t)img * H + y0) * W + 2 * tid;

    float2 acc[16];
    #pragma unroll
    for (int r = 0; r < 16; ++r) acc[r] = make_float2(0.f, 0.f);

    #pragma unroll
    for (int i = 0; i < 56; ++i) {
        const int rr = reflect511(y0 - PAD + i);   // wave-uniform
        const float2 v = *(const float2*)(sbase + (size_t)rr * W);
        #pragma unroll
        for (int r = 0; r < 16; ++r) {
            const int j = i - r;
            if (j >= 0 && j < KS) {
                acc[r].x += gk[j] * v.x;
                acc[r].y += gk[j] * v.y;
            }
        }
    }
    #pragma unroll
    for (int r = 0; r < 16; ++r)
        *((float2*)(obase + (size_t)r * W)) = acc[r];
}

// ---------------- Fallback: known-correct fused kernel ----------------
#define TW 64
#define TH 128
#define TMPH (TH + 2 * PAD)  // 168

__global__ __launch_bounds__(256, 3)
void gauss_blur_fused_kernel(const float* __restrict__ x,
                             const float* __restrict__ w,
                             float* __restrict__ out) {
    __shared__ float g_s[KS];
    __shared__ float tmp[TMPH * TW];

    const int tid = threadIdx.x;
    const int bx = blockIdx.x, by = blockIdx.y, bz = blockIdx.z;
    const int c = bz % CH;

    if (tid < KS) {
        const float* wr = w + (size_t)c * KS * KS + (size_t)tid * KS;
        float s = 0.f;
        #pragma unroll
        for (int j = 0; j < KS; ++j) s += wr[j];
        g_s[tid] = s;
    }
    __syncthreads();

    float gr[KS];
    #pragma unroll
    for (int j = 0; j < KS; ++j) gr[j] = uniform_f(g_s[j]);

    const size_t img_off = (size_t)bz * (H * W);
    const float* img = x + img_off;
    const int x_tile = bx * TW;

    for (int gid = tid; gid < TMPH * (TW / 8); gid += 256) {
        const int r  = gid >> 3;
        const int gx = gid & 7;
        const int gy = reflect_idx(by * TH - PAD + r, H);
        const int x0 = x_tile + gx * 8;
        const float* row = img + (size_t)gy * W;

        float buf[48];
        if (x0 >= PAD && x0 + 27 <= W - 1) {
            const float4* p = (const float4*)(row + x0 - PAD);
            #pragma unroll
            for (int m = 0; m < 12; ++m) {
                float4 v = p[m];
                buf[4 * m + 0] = v.x; buf[4 * m + 1] = v.y;
                buf[4 * m + 2] = v.z; buf[4 * m + 3] = v.w;
            }
        } else {
            #pragma unroll
            for (int j = 0; j < 48; ++j)
                buf[j] = row[reflect_idx(x0 - PAD + j, W)];
        }

        float s[8];
        #pragma unroll
        for (int k = 0; k < 8; ++k) s[k] = 0.f;
        #pragma unroll
        for (int j = 0; j < KS; ++j) {
            #pragma unroll
            for (int k = 0; k < 8; ++k) s[k] += gr[j] * buf[j + k];
        }
        float* dstp = &tmp[r * TW + gx * 8];
        #pragma unroll
        for (int k = 0; k < 8; ++k) dstp[k] = s[k];
    }
    __syncthreads();

    const int lx = tid & 63;
    const int yg = tid >> 6;
    float* o = out + img_off;

    #pragma unroll
    for (int cc = 0; cc < 2; ++cc) {
        const int yc = yg * 32 + cc * 16;
        float col[56];
        #pragma unroll
        for (int i = 0; i < 56; ++i)
            col[i] = tmp[(yc + i) * TW + lx];
        #pragma unroll
        for (int y = 0; y < 16; ++y) {
            float s = 0.f;
            #pragma unroll
            for (int j = 0; j < KS; ++j) s += gr[j] * col[y + j];
            o[(size_t)(by * TH + yc + y) * W + x_tile + lx] = s;
        }
    }
}

extern "C" void kernel_launch(void* const* d_in, const int* in_sizes, int n_in,
                              void* d_out, int out_size, void* d_ws, size_t ws_size,
                              hipStream_t stream) {
    const float* x = (const float*)d_in[0];   // [16,6,512,512]
    const float* w = (const float*)d_in[1];   // [6,1,41,41]
    float* out = (float*)d_out;
    (void)in_sizes; (void)n_in; (void)out_size;

    const size_t need = (size_t)16 * CH * H * W * sizeof(float);
    if (ws_size >= need) {
        float* ws = (float*)d_ws;
        gauss_h_kernel<<<dim3(H / 4, 16 * CH), 256, 0, stream>>>(x, w, ws);
        gauss_v_kernel<<<dim3(H / 16, 16 * CH), 256, 0, stream>>>(ws, w, out);
    } else {
        dim3 grid(W / TW, H / TH, 16 * CH);
        gauss_blur_fused_kernel<<<grid, 256, 0, stream>>>(x, w, out);
    }
}

// Round 4
// 243.376 us; speedup vs baseline: 2.2609x; 1.0827x over previous
//
#include <hip/hip_runtime.h>

#define KS 41
#define PAD 20
#define H 512
#define W 512
#define CH 6

__device__ __forceinline__ int reflect_idx(int i, int n) {
    if (i < 0) i = -i;
    if (i >= n) i = 2 * n - 2 - i;
    return i;
}

__device__ __forceinline__ int reflect511(int i) {
    // valid for i in (-512, 1022)
    return (H - 1) - abs((H - 1) - abs(i));
}

__device__ __forceinline__ float uniform_f(float v) {
    return __uint_as_float(__builtin_amdgcn_readfirstlane(__float_as_uint(v)));
}

// Coefficients -> SGPRs with no LDS and no barrier: lane j (j<41) computes
// row-sum j of the separable 2D kernel, then v_readlane broadcasts each.
__device__ __forceinline__ void load_coeffs(const float* __restrict__ w, int c,
                                            int lane, float gk[KS]) {
    float my = 0.f;
    if (lane < KS) {
        const float* wr = w + (size_t)c * KS * KS + (size_t)lane * KS;
        #pragma unroll
        for (int j = 0; j < KS; ++j) my += wr[j];
    }
    #pragma unroll
    for (int j = 0; j < KS; ++j)
        gk[j] = __uint_as_float(__builtin_amdgcn_readlane(__float_as_uint(my), j));
}

// XOR-swizzled LDS quad addressing: phys quad = q ^ ((q>>3)&7).
// Makes 16B/32B lane-stride b128 accesses hit all 32 banks at min phases.
__device__ __forceinline__ void st4_swz(float* L, int q, float4 v) {
    const int pq = q ^ ((q >> 3) & 7);
    *(float4*)(L + 4 * pq) = v;
}
__device__ __forceinline__ float4 ld4_swz(const float* L, int q) {
    const int pq = q ^ ((q >> 3) & 7);
    return *(const float4*)(L + 4 * pq);
}
__device__ __forceinline__ int swz(int p) {           // float-granular
    return p ^ (((p >> 5) & 7) << 2);
}

// ---------------- Pass 1: horizontal blur, x -> ws ----------------
// One wave per row, per-wave swizzled LDS buffer, NO block barriers.
// Lane l computes 8 consecutive outputs x=8l..8l+7 (12 b128 window reads).
__global__ __launch_bounds__(256, 4)
void gauss_h_kernel(const float* __restrict__ x, const float* __restrict__ w,
                    float* __restrict__ ws) {
    __shared__ float rowbuf[4][560];   // 552 used (padded row), swizzled quads

    const int tid = threadIdx.x;
    const int wv  = tid >> 6;
    const int l   = tid & 63;
    const int img = blockIdx.y;              // 0..95 (= b*CH + c)
    const int c   = img % CH;
    const int row = blockIdx.x * 4 + wv;     // 0..511

    float gk[KS];
    load_coeffs(w, c, l, gk);

    // stage row: lane l holds quads l and l+64; padded coord p = x + 20,
    // so x-quad qx maps to padded quad qx + 5.
    const float4* src4 = (const float4*)(x + ((size_t)img * H + row) * W);
    float4 v0 = src4[l];
    float4 v1 = src4[l + 64];
    float* L = rowbuf[wv];
    st4_swz(L, l + 5, v0);
    st4_swz(L, l + 69, v1);
    __builtin_amdgcn_wave_barrier();

    // reflect halo (scalar, 40 lanes): p<20 <- p'=40-p ; p=532..551 <- p'=1062-p
    if (l < 2 * PAD) {
        const int dstp = (l < PAD) ? l        : (512 + l);   // 0..19 | 532..551
        const int srcp = (l < PAD) ? (40 - l) : (550 - l);   // 40..21 | 530..511
        float hv = L[swz(srcp)];
        L[swz(dstp)] = hv;
    }
    __builtin_amdgcn_wave_barrier();

    // window: padded floats 8l .. 8l+47 = quads 2l .. 2l+11
    float win[48];
    #pragma unroll
    for (int m = 0; m < 12; ++m) {
        float4 q = ld4_swz(L, 2 * l + m);
        win[4 * m + 0] = q.x; win[4 * m + 1] = q.y;
        win[4 * m + 2] = q.z; win[4 * m + 3] = q.w;
    }

    float acc[8];
    #pragma unroll
    for (int i = 0; i < 8; ++i) acc[i] = 0.f;
    #pragma unroll
    for (int j = 0; j < KS; ++j) {
        const float gj = gk[j];
        #pragma unroll
        for (int i = 0; i < 8; ++i) acc[i] += gj * win[j + i];
    }

    float* dst = ws + ((size_t)img * H + row) * W + 8 * l;
    *(float4*)(dst)     = make_float4(acc[0], acc[1], acc[2], acc[3]);
    *(float4*)(dst + 4) = make_float4(acc[4], acc[5], acc[6], acc[7]);
}

// ---------------- Pass 2: vertical blur, ws -> out ----------------
// Block = 128 rows x 64 cols of output. Stage 168x64 ws tile (reflect rows)
// into LDS once, then sliding-column vertical conv (conflict-free reads).
#define VTW 64
#define VTH 128
#define VTMPH (VTH + 2 * PAD)   // 168

__global__ __launch_bounds__(256, 3)
void gauss_v_kernel(const float* __restrict__ ws, const float* __restrict__ w,
                    float* __restrict__ out) {
    __shared__ float tmp[VTMPH * VTW];   // 43008 B

    const int tid = threadIdx.x;
    const int bx  = blockIdx.x;          // 0..7  x strip
    const int by  = blockIdx.y;          // 0..3  y tile
    const int img = blockIdx.z;          // 0..95
    const int c   = img % CH;

    float gk[KS];
    load_coeffs(w, c, tid & 63, gk);

    // stage: 168 rows x 16 quads
    const float* sbase = ws + (size_t)img * H * W + bx * VTW;
    for (int idx = tid; idx < VTMPH * 16; idx += 256) {
        const int r  = idx >> 4;
        const int q  = idx & 15;
        const int sr = reflect511(by * VTH - PAD + r);
        float4 v = *(const float4*)(sbase + (size_t)sr * W + 4 * q);
        *(float4*)&tmp[r * VTW + 4 * q] = v;
    }
    __syncthreads();

    const int lx = tid & 63;
    const int yg = tid >> 6;   // 0..3
    float* o = out + ((size_t)img * H + by * VTH) * W + bx * VTW + lx;

    #pragma unroll
    for (int cc = 0; cc < 2; ++cc) {
        const int yc = yg * 32 + cc * 16;
        float col[56];
        #pragma unroll
        for (int i = 0; i < 56; ++i)
            col[i] = tmp[(yc + i) * VTW + lx];   // 4B lane stride: conflict-free
        #pragma unroll
        for (int y = 0; y < 16; ++y) {
            float s = 0.f;
            #pragma unroll
            for (int j = 0; j < KS; ++j) s += gk[j] * col[y + j];
            o[(size_t)(yc + y) * W] = s;
        }
    }
}

// ---------------- Fallback: known-correct fused kernel ----------------
#define TW 64
#define TH 128
#define TMPH (TH + 2 * PAD)  // 168

__global__ __launch_bounds__(256, 3)
void gauss_blur_fused_kernel(const float* __restrict__ x,
                             const float* __restrict__ w,
                             float* __restrict__ out) {
    __shared__ float g_s[KS];
    __shared__ float tmp[TMPH * TW];

    const int tid = threadIdx.x;
    const int bx = blockIdx.x, by = blockIdx.y, bz = blockIdx.z;
    const int c = bz % CH;

    if (tid < KS) {
        const float* wr = w + (size_t)c * KS * KS + (size_t)tid * KS;
        float s = 0.f;
        #pragma unroll
        for (int j = 0; j < KS; ++j) s += wr[j];
        g_s[tid] = s;
    }
    __syncthreads();

    float gr[KS];
    #pragma unroll
    for (int j = 0; j < KS; ++j) gr[j] = uniform_f(g_s[j]);

    const size_t img_off = (size_t)bz * (H * W);
    const float* img = x + img_off;
    const int x_tile = bx * TW;

    for (int gid = tid; gid < TMPH * (TW / 8); gid += 256) {
        const int r  = gid >> 3;
        const int gx = gid & 7;
        const int gy = reflect_idx(by * TH - PAD + r, H);
        const int x0 = x_tile + gx * 8;
        const float* row = img + (size_t)gy * W;

        float buf[48];
        if (x0 >= PAD && x0 + 27 <= W - 1) {
            const float4* p = (const float4*)(row + x0 - PAD);
            #pragma unroll
            for (int m = 0; m < 12; ++m) {
                float4 v = p[m];
                buf[4 * m + 0] = v.x; buf[4 * m + 1] = v.y;
                buf[4 * m + 2] = v.z; buf[4 * m + 3] = v.w;
            }
        } else {
            #pragma unroll
            for (int j = 0; j < 48; ++j)
                buf[j] = row[reflect_idx(x0 - PAD + j, W)];
        }

        float s[8];
        #pragma unroll
        for (int k = 0; k < 8; ++k) s[k] = 0.f;
        #pragma unroll
        for (int j = 0; j < KS; ++j) {
            #pragma unroll
            for (int k = 0; k < 8; ++k) s[k] += gr[j] * buf[j + k];
        }
        float* dstp = &tmp[r * TW + gx * 8];
        #pragma unroll
        for (int k = 0; k < 8; ++k) dstp[k] = s[k];
    }
    __syncthreads();

    const int lx = tid & 63;
    const int yg = tid >> 6;
    float* o = out + img_off;

    #pragma unroll
    for (int cc = 0; cc < 2; ++cc) {
        const int yc = yg * 32 + cc * 16;
        float col[56];
        #pragma unroll
        for (int i = 0; i < 56; ++i)
            col[i] = tmp[(yc + i) * TW + lx];
        #pragma unroll
        for (int y = 0; y < 16; ++y) {
            float s = 0.f;
            #pragma unroll
            for (int j = 0; j < KS; ++j) s += gr[j] * col[y + j];
            o[(size_t)(by * TH + yc + y) * W + x_tile + lx] = s;
        }
    }
}

extern "C" void kernel_launch(void* const* d_in, const int* in_sizes, int n_in,
                              void* d_out, int out_size, void* d_ws, size_t ws_size,
                              hipStream_t stream) {
    const float* x = (const float*)d_in[0];   // [16,6,512,512]
    const float* w = (const float*)d_in[1];   // [6,1,41,41]
    float* out = (float*)d_out;
    (void)in_sizes; (void)n_in; (void)out_size;

    const size_t need = (size_t)16 * CH * H * W * sizeof(float);
    if (ws_size >= need) {
        float* ws = (float*)d_ws;
        gauss_h_kernel<<<dim3(H / 4, 16 * CH), 256, 0, stream>>>(x, w, ws);
        gauss_v_kernel<<<dim3(W / VTW, H / VTH, 16 * CH), 256, 0, stream>>>(ws, w, out);
    } else {
        dim3 grid(W / TW, H / TH, 16 * CH);
        gauss_blur_fused_kernel<<<grid, 256, 0, stream>>>(x, w, out);
    }
}